// Round 6
// baseline (257.273 us; speedup 1.0000x reference)
//
#include <hip/hip_runtime.h>
#include <cstdint>
#include <cstddef>

// ---------- types & helpers ----------
typedef __attribute__((ext_vector_type(4))) float f32x4;
typedef __attribute__((ext_vector_type(8))) short bf16x8;
typedef __attribute__((ext_vector_type(4))) unsigned short u16x4;
typedef __attribute__((ext_vector_type(8))) unsigned short u16x8;

#define GPTR(p) ((const __attribute__((address_space(1))) void*)(p))
#define LPTR(p) ((__attribute__((address_space(3))) void*)(p))

static constexpr int BB = 4096;  // batch rows
static constexpr int DD = 1024;  // feature dim
static constexpr int FF = 8192;  // memory slots
static constexpr int MM = 256;   // attention key dim

__device__ __forceinline__ unsigned short f2bf(float f) {
    union { float f; unsigned u; } x; x.f = f;
    return (unsigned short)((x.u + 0x7FFFu + ((x.u >> 16) & 1u)) >> 16);  // RNE
}
__device__ __forceinline__ float bf2f(unsigned short h) {
    union { unsigned u; float f; } x; x.u = ((unsigned)h) << 16;
    return x.f;
}
// bijective XCD swizzle (grid % 8 == 0)
__device__ __forceinline__ int xcd_swz(int bid, int grid) {
    const int cpx = grid >> 3;
    return (bid & 7) * cpx + (bid >> 3);
}

// ---------- f32 -> bf16 convert ----------
__global__ __launch_bounds__(256) void cvt_bf16(const float* __restrict__ in,
                                                unsigned short* __restrict__ out, int n) {
    int i = (blockIdx.x * 256 + threadIdx.x) * 4;
    if (i >= n) return;
    f32x4 v = *(const f32x4*)(in + i);
    u16x4 o;
    o.x = f2bf(v.x); o.y = f2bf(v.y); o.z = f2bf(v.z); o.w = f2bf(v.w);
    *(u16x4*)(out + i) = o;
}

// merged convert of the three weight matrices (one launch)
__global__ __launch_bounds__(256) void cvt_w(
    const float* __restrict__ Wq, const float* __restrict__ Wk, const float* __restrict__ Wv,
    unsigned short* __restrict__ Wqb, unsigned short* __restrict__ Wkb, unsigned short* __restrict__ Wvb)
{
    int i = (blockIdx.x * 256 + threadIdx.x) * 4;
    const float* in; unsigned short* out; int off;
    if (i < MM * DD)            { in = Wq; out = Wqb; off = 0; }
    else if (i < 2 * MM * DD)   { in = Wk; out = Wkb; off = MM * DD; }
    else                        { in = Wv; out = Wvb; off = 2 * MM * DD; }
    const int j = i - off;
    f32x4 v = *(const f32x4*)(in + j);
    u16x4 o;
    o.x = f2bf(v.x); o.y = f2bf(v.y); o.z = f2bf(v.z); o.w = f2bf(v.w);
    *(u16x4*)(out + j) = o;
}

// ---------- 128x128 GEMM (m97 structure) for the small Q/K projections ----------
template<int Mo, int No, int Kd, int KC>
__global__ __launch_bounds__(256) void gemm_t(
    const unsigned short* __restrict__ A,
    const unsigned short* __restrict__ Bm,
    unsigned short* __restrict__ P)       // [KC][Mo][No] bf16 partials
{
    constexpr int mt = Mo >> 7, nt = No >> 7;
    constexpr int chunk = Kd / KC;

    __shared__ alignas(16) unsigned short As[128 * 32];
    __shared__ alignas(16) unsigned short Bs[128 * 32];

    const int tid  = threadIdx.x;
    const int lane = tid & 63;
    const int wid  = tid >> 6;
    const int L = xcd_swz(blockIdx.x, KC * mt * nt);
    const int tm = (L % mt) << 7;
    const int r  = L / mt;
    const int tn = (r % nt) << 7;
    const int kc = r / nt;
    const int kbase = kc * chunk;
    const int wm = (wid >> 1) * 64;
    const int wn = (wid & 1) * 64;
    const int lr = lane & 15;
    const int lg = lane >> 4;

    f32x4 acc[4][4] = {};

    const int srow = tid >> 2;
    const int scol = (tid & 3) << 3;
    const unsigned short* aptr = A  + (size_t)(tm + srow) * Kd + kbase + scol;
    const unsigned short* bptr = Bm + (size_t)(tn + srow) * Kd + kbase + scol;
    unsigned short* As_base = &As[wid * 512];   // HW adds lane*16B
    unsigned short* Bs_base = &Bs[wid * 512];

    for (int k0 = 0; k0 < chunk; k0 += 32) {
        __builtin_amdgcn_global_load_lds(GPTR(aptr + k0),                   LPTR(As_base),        16, 0, 0);
        __builtin_amdgcn_global_load_lds(GPTR(aptr + (size_t)64 * Kd + k0), LPTR(As_base + 2048), 16, 0, 0);
        __builtin_amdgcn_global_load_lds(GPTR(bptr + k0),                   LPTR(Bs_base),        16, 0, 0);
        __builtin_amdgcn_global_load_lds(GPTR(bptr + (size_t)64 * Kd + k0), LPTR(Bs_base + 2048), 16, 0, 0);
        __syncthreads();

        bf16x8 af[4], bfr[4];
        #pragma unroll
        for (int mi = 0; mi < 4; ++mi)
            af[mi] = *(const bf16x8*)&As[(wm + mi * 16 + lr) * 32 + lg * 8];
        #pragma unroll
        for (int ni = 0; ni < 4; ++ni)
            bfr[ni] = *(const bf16x8*)&Bs[(wn + ni * 16 + lr) * 32 + lg * 8];

        #pragma unroll
        for (int mi = 0; mi < 4; ++mi)
            #pragma unroll
            for (int ni = 0; ni < 4; ++ni)
                acc[mi][ni] = __builtin_amdgcn_mfma_f32_16x16x32_bf16(af[mi], bfr[ni], acc[mi][ni], 0, 0, 0);
        __syncthreads();
    }

    unsigned short* Pk = P + (size_t)kc * Mo * No;
    #pragma unroll
    for (int mi = 0; mi < 4; ++mi)
        #pragma unroll
        for (int ni = 0; ni < 4; ++ni)
            #pragma unroll
            for (int r2 = 0; r2 < 4; ++r2) {
                const int row = tm + wm + mi * 16 + lg * 4 + r2;
                const int col = tn + wn + ni * 16 + lr;
                Pk[(size_t)row * No + col] = f2bf(acc[mi][ni][r2]);
            }
}

// ---------- 256x256 deep-pipelined GEMM (verified structure from round 5) ----------
// A[Mo][Kd], B[No][Kd] bf16. 8 waves (2M x 4N), BK=32, 4-buffer LDS ring,
// stage distance 3, counted vmcnt(8)/(4)/(0). BK=32 row stride 64B: fragment
// ds_read_b128 spreads over all 32 banks, no swizzle; staging linear for gload_lds.
// DIRECT=1: write bf16 C directly. DIRECT=0: bf16 partials P[kc][Mo][No].
template<int Mo, int No, int Kd, int KC, int DIRECT>
__global__ __launch_bounds__(512) void gemm256(
    const unsigned short* __restrict__ A,
    const unsigned short* __restrict__ Bm,
    unsigned short* __restrict__ Out)
{
    constexpr int KCH = Kd / KC;
    constexpr int NT  = KCH / 32;
    constexpr int mt  = Mo >> 8;
    constexpr int nt  = No >> 8;

    __shared__ alignas(16) unsigned short SH[4 * 16384];  // 128 KB ring

    const int tid  = threadIdx.x;
    const int lane = tid & 63;
    const int wid  = tid >> 6;
    const int wr   = wid >> 2;
    const int wc   = wid & 3;
    const int lr   = lane & 15;
    const int lg   = lane >> 4;

    const int L  = xcd_swz(blockIdx.x, KC * mt * nt);
    const int tn = (L % nt) << 8;
    const int r0 = L / nt;
    const int tm = (r0 % mt) << 8;
    const int kc = r0 / mt;
    const size_t kbase = (size_t)kc * KCH;

    const unsigned short* ag0 = A  + (size_t)(tm + (tid >> 2)) * Kd + kbase + ((tid & 3) << 3);
    const unsigned short* bg0 = Bm + (size_t)(tn + (tid >> 2)) * Kd + kbase + ((tid & 3) << 3);

    auto STAGE_A = [&](int tt) {
        const int buf = tt & 3;
        #pragma unroll
        for (int s = 0; s < 2; ++s)
            __builtin_amdgcn_global_load_lds(GPTR(ag0 + (size_t)(s * 128) * Kd + tt * 32),
                LPTR(&SH[buf * 16384 + s * 4096 + wid * 512]), 16, 0, 0);
    };
    auto STAGE_B = [&](int tt) {
        const int buf = tt & 3;
        #pragma unroll
        for (int s = 0; s < 2; ++s)
            __builtin_amdgcn_global_load_lds(GPTR(bg0 + (size_t)(s * 128) * Kd + tt * 32),
                LPTR(&SH[buf * 16384 + 8192 + s * 4096 + wid * 512]), 16, 0, 0);
    };

    f32x4 acc[8][4] = {};

    STAGE_A(0); STAGE_B(0);
    STAGE_A(1); STAGE_B(1);
    STAGE_A(2); STAGE_B(2);
    asm volatile("s_waitcnt vmcnt(8)" ::: "memory");
    __builtin_amdgcn_s_barrier();

    #pragma unroll 1
    for (int t = 0; t < NT; ++t) {
        if (t) {
            if (t < NT - 2)      asm volatile("s_waitcnt vmcnt(8)" ::: "memory");
            else if (t == NT-2)  asm volatile("s_waitcnt vmcnt(4)" ::: "memory");
            else                 asm volatile("s_waitcnt vmcnt(0)" ::: "memory");
            __builtin_amdgcn_s_barrier();
        }
        const int buf = t & 3;
        const unsigned short* Ab = &SH[buf * 16384];
        const unsigned short* Bb = &SH[buf * 16384 + 8192];

        // phase 1: read B(all) + A(lo); stage A(t+3); 16 MFMA
        bf16x8 bfr[4], af[4];
        #pragma unroll
        for (int ni = 0; ni < 4; ++ni)
            bfr[ni] = *(const bf16x8*)&Bb[(wc * 64 + ni * 16 + lr) * 32 + lg * 8];
        #pragma unroll
        for (int mi = 0; mi < 4; ++mi)
            af[mi] = *(const bf16x8*)&Ab[(wr * 128 + mi * 16 + lr) * 32 + lg * 8];
        if (t + 3 < NT) STAGE_A(t + 3);
        __builtin_amdgcn_sched_barrier(0);
        __builtin_amdgcn_s_setprio(1);
        #pragma unroll
        for (int mi = 0; mi < 4; ++mi)
            #pragma unroll
            for (int ni = 0; ni < 4; ++ni)
                acc[mi][ni] = __builtin_amdgcn_mfma_f32_16x16x32_bf16(af[mi], bfr[ni], acc[mi][ni], 0, 0, 0);
        __builtin_amdgcn_s_setprio(0);
        __builtin_amdgcn_s_barrier();

        // phase 2: read A(hi); stage B(t+3); 16 MFMA
        bf16x8 af2[4];
        #pragma unroll
        for (int mi = 0; mi < 4; ++mi)
            af2[mi] = *(const bf16x8*)&Ab[(wr * 128 + 64 + mi * 16 + lr) * 32 + lg * 8];
        if (t + 3 < NT) STAGE_B(t + 3);
        __builtin_amdgcn_sched_barrier(0);
        __builtin_amdgcn_s_setprio(1);
        #pragma unroll
        for (int mi = 0; mi < 4; ++mi)
            #pragma unroll
            for (int ni = 0; ni < 4; ++ni)
                acc[4 + mi][ni] = __builtin_amdgcn_mfma_f32_16x16x32_bf16(af2[mi], bfr[ni], acc[4 + mi][ni], 0, 0, 0);
        __builtin_amdgcn_s_setprio(0);
    }

    unsigned short* Ok = DIRECT ? (Out + (size_t)tm * No + tn)
                                : (Out + ((size_t)kc * Mo + tm) * No + tn);
    #pragma unroll
    for (int mi = 0; mi < 8; ++mi)
        #pragma unroll
        for (int ni = 0; ni < 4; ++ni)
            #pragma unroll
            for (int r = 0; r < 4; ++r) {
                const int row = wr * 128 + mi * 16 + lg * 4 + r;
                const int col = wc * 64 + ni * 16 + lr;
                Ok[(size_t)row * No + col] = f2bf(acc[mi][ni][r]);
            }
}

// ---------- reduce KC bf16 partials ----------
// MODE 0: f32 out, no bias. MODE 1: bf16 out, (v + bias[i & NoMask]) * scale.
// MODE 2: bf16 out, v + bias[i >> SHIFT] (by-row bias).
template<int KC, int MODE, int SHIFT = 0>
__global__ __launch_bounds__(256) void reduce_sk(
    const unsigned short* __restrict__ P, void* __restrict__ out,
    const float* __restrict__ bias, size_t total, int NoMask, float scale)
{
    const size_t i = ((size_t)blockIdx.x * 256 + threadIdx.x) * 8;
    float v[8] = {0,0,0,0,0,0,0,0};
    #pragma unroll
    for (int kc = 0; kc < KC; ++kc) {
        u16x8 p = *(const u16x8*)(P + kc * total + i);
        #pragma unroll
        for (int c = 0; c < 8; ++c) v[c] += bf2f(p[c]);
    }
    if (MODE == 1) {
        u16x8 o;
        #pragma unroll
        for (int c = 0; c < 8; ++c)
            o[c] = f2bf((v[c] + bias[(i + c) & NoMask]) * scale);
        *(u16x8*)((unsigned short*)out + i) = o;
    } else if (MODE == 2) {
        const float b = bias[i >> SHIFT];   // row constant across the 8-vector
        u16x8 o;
        #pragma unroll
        for (int c = 0; c < 8; ++c) o[c] = f2bf(v[c] + b);
        *(u16x8*)((unsigned short*)out + i) = o;
    } else {
        f32x4 o0, o1;
        #pragma unroll
        for (int c = 0; c < 4; ++c) { o0[c] = v[c]; o1[c] = v[4 + c]; }
        *(f32x4*)((float*)out + i)     = o0;
        *(f32x4*)((float*)out + i + 4) = o1;
    }
}

// ---------- sparsemax over rows of bf16 scores; attn f32 out + attn bf16 in place ----------
__global__ __launch_bounds__(256) void sparsemax_k(unsigned short* __restrict__ SA,
                                                   float* __restrict__ attn)
{
    __shared__ float red[16];
    const int t = threadIdx.x;
    const int w = t >> 6, lane = t & 63;
    unsigned short* Zrow = SA + (size_t)blockIdx.x * FF;
    float* Arow = attn + (size_t)blockIdx.x * FF;

    f32x4 z[8];
    #pragma unroll
    for (int j = 0; j < 4; ++j) {
        u16x8 v = *(const u16x8*)&Zrow[j * 2048 + t * 8];
        #pragma unroll
        for (int c = 0; c < 4; ++c) {
            z[2 * j][c]     = bf2f(v[c]);
            z[2 * j + 1][c] = bf2f(v[4 + c]);
        }
    }

    float mx = -1e30f, sm = 0.0f;
    #pragma unroll
    for (int j = 0; j < 8; ++j)
        #pragma unroll
        for (int c = 0; c < 4; ++c) { mx = fmaxf(mx, z[j][c]); sm += z[j][c]; }
    #pragma unroll
    for (int off = 32; off > 0; off >>= 1) {
        mx = fmaxf(mx, __shfl_xor(mx, off));
        sm += __shfl_xor(sm, off);
    }
    if (lane == 0) { red[w] = mx; red[8 + w] = sm; }
    __syncthreads();
    mx = fmaxf(fmaxf(red[0], red[1]), fmaxf(red[2], red[3]));
    sm = red[8] + red[9] + red[10] + red[11];
    __syncthreads();

    float lo = fmaxf(mx - 1.0f, (sm - 1.0f) * (1.0f / (float)FF));
    float hi = mx - 1.0f / (float)FF;

    for (int it = 0; it < 8; ++it) {
        const float mid = 0.5f * (lo + hi);
        float s = 0.0f;
        #pragma unroll
        for (int j = 0; j < 8; ++j)
            #pragma unroll
            for (int c = 0; c < 4; ++c) s += fmaxf(z[j][c] - mid, 0.0f);
        #pragma unroll
        for (int off = 32; off > 0; off >>= 1) s += __shfl_xor(s, off);
        if (lane == 0) red[w] = s;
        __syncthreads();
        s = red[0] + red[1] + red[2] + red[3];
        __syncthreads();
        if (s >= 1.0f) lo = mid; else hi = mid;
    }

    for (int it = 0; it < 2; ++it) {
        float s = 0.0f, cnt = 0.0f;
        #pragma unroll
        for (int j = 0; j < 8; ++j)
            #pragma unroll
            for (int c = 0; c < 4; ++c) {
                const float v = z[j][c];
                if (v > lo) { s += v; cnt += 1.0f; }
            }
        #pragma unroll
        for (int off = 32; off > 0; off >>= 1) { s += __shfl_xor(s, off); cnt += __shfl_xor(cnt, off); }
        if (lane == 0) { red[w] = s; red[8 + w] = cnt; }
        __syncthreads();
        s   = red[0] + red[1] + red[2] + red[3];
        cnt = red[8] + red[9] + red[10] + red[11];
        __syncthreads();
        lo = (s - 1.0f) / cnt;
    }
    const float tau = lo;

    #pragma unroll
    for (int j = 0; j < 4; ++j) {
        f32x4 a0, a1;
        #pragma unroll
        for (int c = 0; c < 4; ++c) {
            a0[c] = fmaxf(z[2 * j][c] - tau, 0.0f);
            a1[c] = fmaxf(z[2 * j + 1][c] - tau, 0.0f);
        }
        *(f32x4*)&Arow[j * 2048 + t * 8]     = a0;
        *(f32x4*)&Arow[j * 2048 + t * 8 + 4] = a1;
        u16x8 o;
        #pragma unroll
        for (int c = 0; c < 4; ++c) { o[c] = f2bf(a0[c]); o[4 + c] = f2bf(a1[c]); }
        *(u16x8*)&Zrow[j * 2048 + t * 8] = o;
    }
}

// ---------- launch ----------
extern "C" void kernel_launch(void* const* d_in, const int* in_sizes, int n_in,
                              void* d_out, int out_size, void* d_ws, size_t ws_size,
                              hipStream_t stream) {
    const float* x  = (const float*)d_in[0];
    const float* Xd = (const float*)d_in[1];
    const float* Wq = (const float*)d_in[2];
    const float* bq = (const float*)d_in[3];
    const float* Wk = (const float*)d_in[4];
    const float* bk = (const float*)d_in[5];
    const float* Wv = (const float*)d_in[6];
    const float* bv = (const float*)d_in[7];

    float* out       = (float*)d_out;
    float* out_xhat  = out + (size_t)BB * DD;
    float* out_attn  = out + (size_t)2 * BB * DD;

    char* w = (char*)d_ws;
    unsigned short* xb  = (unsigned short*)w; w += (size_t)BB * DD * 2;   //  0-8 MB
    unsigned short* Xb  = (unsigned short*)w; w += (size_t)FF * DD * 2;   //  8-24 MB
    unsigned short* Wqb = (unsigned short*)w; w += (size_t)MM * DD * 2;
    unsigned short* Wkb = (unsigned short*)w; w += (size_t)MM * DD * 2;
    unsigned short* Wvb = (unsigned short*)w; w += (size_t)DD * DD * 2;
    unsigned short* Qb  = (unsigned short*)w; w += (size_t)BB * MM * 2;
    unsigned short* Kb  = (unsigned short*)w; w += (size_t)FF * MM * 2;   // ..33 MB
    unsigned short* Vtb = (unsigned short*)w; w += (size_t)DD * FF * 2;   // 33-49 MB
    unsigned short* Sb  = (unsigned short*)w; w += (size_t)BB * FF * 2;   // 49-113 MB

    // overlays (all lifetimes disjoint on the serial stream):
    unsigned short* Pb = (unsigned short*)d_ws;  // xhat partials 32 MB over xb..Kb (dead at xhat time)
    unsigned short* PV = Sb;                     // Vt partials 32 MB over Sb (dead until scores)
    unsigned short* PQ = (unsigned short*)out_attn;          // Q partials 16 MB in attn region
    unsigned short* PK = PQ + (size_t)8 * BB * MM;           // K partials 16 MB in attn region

    hipMemcpyAsync(d_out, d_in[0], (size_t)BB * DD * sizeof(float),
                   hipMemcpyDeviceToDevice, stream);

    cvt_bf16<<<BB * DD / 1024, 256, 0, stream>>>(x,  xb,  BB * DD);
    cvt_bf16<<<FF * DD / 1024, 256, 0, stream>>>(Xd, Xb,  FF * DD);
    cvt_w<<<(2 * MM * DD + DD * DD) / 1024, 256, 0, stream>>>(Wq, Wk, Wv, Wqb, Wkb, Wvb);

    const float scl = 0.0625f;  // 1/sqrt(256)

    // Q = (x @ Wq^T + bq) * scl   split-K x8, grid 512
    gemm_t<BB, MM, DD, 8><<<8 * (BB/128) * (MM/128), 256, 0, stream>>>(xb, Wqb, PQ);
    // K = (X @ Wk^T + bk) * scl   split-K x4, grid 512
    gemm_t<FF, MM, DD, 4><<<4 * (FF/128) * (MM/128), 256, 0, stream>>>(Xb, Wkb, PK);
    reduce_sk<8, 1><<<BB * MM / 2048, 256, 0, stream>>>(PQ, Qb, bq, (size_t)BB * MM, MM - 1, scl);
    reduce_sk<4, 1><<<FF * MM / 2048, 256, 0, stream>>>(PK, Kb, bk, (size_t)FF * MM, MM - 1, scl);

    // Vt = Wv @ X^T + bv[row]  256x256 deep-pipe split-K x2 -> PV -> Vtb (+bias)
    gemm256<DD, FF, DD, 2, 0><<<2 * (DD/256) * (FF/256), 512, 0, stream>>>(Wvb, Xb, PV);
    reduce_sk<2, 2, 13><<<DD * FF / 2048, 256, 0, stream>>>(PV, Vtb, bv, (size_t)DD * FF, 0, 1.0f);

    // scores = Q @ K^T  256x256 deep-pipe direct bf16 -> Sb
    gemm256<BB, FF, MM, 1, 1><<<(BB/256) * (FF/256), 512, 0, stream>>>(Qb, Kb, Sb);

    // sparsemax: attn f32 -> d_out, attn bf16 in place over Sb
    sparsemax_k<<<BB, 256, 0, stream>>>(Sb, out_attn);

    // x_hat = attn @ Vt^T  256x256 deep-pipe split-K x4 -> Pb -> f32 out
    gemm256<BB, DD, FF, 4, 0><<<4 * (BB/256) * (DD/256), 512, 0, stream>>>(Sb, Vtb, Pb);
    reduce_sk<4, 0><<<BB * DD / 2048, 256, 0, stream>>>(Pb, out_xhat, nullptr, (size_t)BB * DD, 0, 1.0f);
}

// Round 7
// 214.309 us; speedup vs baseline: 1.2005x; 1.2005x over previous
//
#include <hip/hip_runtime.h>
#include <cstdint>
#include <cstddef>

// ---------- types & helpers ----------
typedef __attribute__((ext_vector_type(4))) float f32x4;
typedef __attribute__((ext_vector_type(8))) short bf16x8;
typedef __attribute__((ext_vector_type(4))) unsigned short u16x4;
typedef __attribute__((ext_vector_type(8))) unsigned short u16x8;

#define GPTR(p) ((const __attribute__((address_space(1))) void*)(p))
#define LPTR(p) ((__attribute__((address_space(3))) void*)(p))

static constexpr int BB = 4096;  // batch rows
static constexpr int DD = 1024;  // feature dim
static constexpr int FF = 8192;  // memory slots
static constexpr int MM = 256;   // attention key dim

__device__ __forceinline__ unsigned short f2bf(float f) {
    union { float f; unsigned u; } x; x.f = f;
    return (unsigned short)((x.u + 0x7FFFu + ((x.u >> 16) & 1u)) >> 16);  // RNE
}
__device__ __forceinline__ float bf2f(unsigned short h) {
    union { unsigned u; float f; } x; x.u = ((unsigned)h) << 16;
    return x.f;
}
// bijective XCD swizzle (grid % 8 == 0)
__device__ __forceinline__ int xcd_swz(int bid, int grid) {
    const int cpx = grid >> 3;
    return (bid & 7) * cpx + (bid >> 3);
}

// ---------- merged convert: x (f32 passthrough + bf16), X_data, Wq, Wk, Wv ----------
__global__ __launch_bounds__(256) void cvt_all(
    const float* __restrict__ x,  const float* __restrict__ Xd,
    const float* __restrict__ Wq, const float* __restrict__ Wk, const float* __restrict__ Wv,
    float* __restrict__ out_x,
    unsigned short* __restrict__ xb,  unsigned short* __restrict__ Xb,
    unsigned short* __restrict__ Wqb, unsigned short* __restrict__ Wkb, unsigned short* __restrict__ Wvb)
{
    constexpr int S0 = BB * DD;                 // x
    constexpr int S1 = FF * DD;                 // X_data
    constexpr int SW = MM * DD;                 // Wq / Wk each
    const int i = (blockIdx.x * 256 + threadIdx.x) * 4;
    if (i < S0) {
        f32x4 v = *(const f32x4*)(x + i);
        *(f32x4*)(out_x + i) = v;               // passthrough output 0
        u16x4 o; o.x = f2bf(v.x); o.y = f2bf(v.y); o.z = f2bf(v.z); o.w = f2bf(v.w);
        *(u16x4*)(xb + i) = o;
    } else if (i < S0 + S1) {
        const int j = i - S0;
        f32x4 v = *(const f32x4*)(Xd + j);
        u16x4 o; o.x = f2bf(v.x); o.y = f2bf(v.y); o.z = f2bf(v.z); o.w = f2bf(v.w);
        *(u16x4*)(Xb + j) = o;
    } else {
        int j = i - S0 - S1;
        const float* in; unsigned short* outp;
        if (j < SW)            { in = Wq; outp = Wqb; }
        else if (j < 2 * SW)   { in = Wk; outp = Wkb; j -= SW; }
        else                   { in = Wv; outp = Wvb; j -= 2 * SW; }
        f32x4 v = *(const f32x4*)(in + j);
        u16x4 o; o.x = f2bf(v.x); o.y = f2bf(v.y); o.z = f2bf(v.z); o.w = f2bf(v.w);
        *(u16x4*)(outp + j) = o;
    }
}

// ---------- 128x128 GEMM core (m97 structure), direct bf16 out + fused bias ----------
// BIAS_MODE: 0 none, 1 (v+bias[col])*scale, 2 v+bias[row]
template<int Mo, int No, int Kd, int BIAS_MODE>
__device__ __forceinline__ void gemm128_core(
    const unsigned short* __restrict__ A,
    const unsigned short* __restrict__ Bm,
    unsigned short* __restrict__ Out,
    const float* __restrict__ bias, float scale,
    int L, unsigned short* As, unsigned short* Bs)
{
    constexpr int mt = Mo >> 7, nt = No >> 7;
    const int tid  = threadIdx.x;
    const int lane = tid & 63;
    const int wid  = tid >> 6;
    const int tm = (L % mt) << 7;            // tm fastest: consecutive blocks share B-tile
    const int tn = ((L / mt) % nt) << 7;
    const int wm = (wid >> 1) * 64;
    const int wn = (wid & 1) * 64;
    const int lr = lane & 15;
    const int lg = lane >> 4;

    f32x4 acc[4][4] = {};

    const unsigned short* aptr = A  + (size_t)(tm + (tid >> 2)) * Kd + ((tid & 3) << 3);
    const unsigned short* bptr = Bm + (size_t)(tn + (tid >> 2)) * Kd + ((tid & 3) << 3);
    unsigned short* As_base = &As[wid * 512];   // HW adds lane*16B
    unsigned short* Bs_base = &Bs[wid * 512];

    for (int k0 = 0; k0 < Kd; k0 += 32) {
        __builtin_amdgcn_global_load_lds(GPTR(aptr + k0),                   LPTR(As_base),        16, 0, 0);
        __builtin_amdgcn_global_load_lds(GPTR(aptr + (size_t)64 * Kd + k0), LPTR(As_base + 2048), 16, 0, 0);
        __builtin_amdgcn_global_load_lds(GPTR(bptr + k0),                   LPTR(Bs_base),        16, 0, 0);
        __builtin_amdgcn_global_load_lds(GPTR(bptr + (size_t)64 * Kd + k0), LPTR(Bs_base + 2048), 16, 0, 0);
        __syncthreads();

        bf16x8 af[4], bfr[4];
        #pragma unroll
        for (int mi = 0; mi < 4; ++mi)
            af[mi] = *(const bf16x8*)&As[(wm + mi * 16 + lr) * 32 + lg * 8];
        #pragma unroll
        for (int ni = 0; ni < 4; ++ni)
            bfr[ni] = *(const bf16x8*)&Bs[(wn + ni * 16 + lr) * 32 + lg * 8];

        #pragma unroll
        for (int mi = 0; mi < 4; ++mi)
            #pragma unroll
            for (int ni = 0; ni < 4; ++ni)
                acc[mi][ni] = __builtin_amdgcn_mfma_f32_16x16x32_bf16(af[mi], bfr[ni], acc[mi][ni], 0, 0, 0);
        __syncthreads();
    }

    #pragma unroll
    for (int mi = 0; mi < 4; ++mi)
        #pragma unroll
        for (int ni = 0; ni < 4; ++ni)
            #pragma unroll
            for (int r = 0; r < 4; ++r) {
                const int row = tm + wm + mi * 16 + lg * 4 + r;
                const int col = tn + wn + ni * 16 + lr;
                float v = acc[mi][ni][r];
                if (BIAS_MODE == 1) v = (v + bias[col]) * scale;
                if (BIAS_MODE == 2) v = v + bias[row];
                Out[(size_t)row * No + col] = f2bf(v);
            }
}

// ---------- merged projection kernel: Vt (512 blocks) + K (128) + Q (64), all co-resident ----------
__global__ __launch_bounds__(256) void proj_all(
    const unsigned short* __restrict__ xb,  const unsigned short* __restrict__ Xb,
    const unsigned short* __restrict__ Wqb, const unsigned short* __restrict__ Wkb,
    const unsigned short* __restrict__ Wvb,
    unsigned short* __restrict__ Qb, unsigned short* __restrict__ Kb, unsigned short* __restrict__ Vtb,
    const float* __restrict__ bq, const float* __restrict__ bk, const float* __restrict__ bv,
    float scl)
{
    __shared__ alignas(16) unsigned short As[128 * 32];
    __shared__ alignas(16) unsigned short Bs[128 * 32];
    const int bid = blockIdx.x;
    if (bid < 512) {
        // Vt = Wv @ X^T + bv[row]   [DD,FF]
        gemm128_core<DD, FF, DD, 2>(Wvb, Xb, Vtb, bv, 1.0f, xcd_swz(bid, 512), As, Bs);
    } else if (bid < 640) {
        // K = (X @ Wk^T + bk) * scl [FF,MM]
        gemm128_core<FF, MM, DD, 1>(Xb, Wkb, Kb, bk, scl, xcd_swz(bid - 512, 128), As, Bs);
    } else {
        // Q = (x @ Wq^T + bq) * scl [BB,MM]
        gemm128_core<BB, MM, DD, 1>(xb, Wqb, Qb, bq, scl, xcd_swz(bid - 640, 64), As, Bs);
    }
}

// ---------- 256x256 deep-pipelined GEMM (verified structure, rounds 5-6) ----------
// 8 waves (2M x 4N), BK=32, 4-buffer LDS ring, stage distance 3, counted vmcnt.
// DIRECT=1: bf16 C. DIRECT=0: bf16 partials P[kc][Mo][No].
template<int Mo, int No, int Kd, int KC, int DIRECT>
__global__ __launch_bounds__(512) void gemm256(
    const unsigned short* __restrict__ A,
    const unsigned short* __restrict__ Bm,
    unsigned short* __restrict__ Out)
{
    constexpr int KCH = Kd / KC;
    constexpr int NT  = KCH / 32;
    constexpr int mt  = Mo >> 8;
    constexpr int nt  = No >> 8;

    __shared__ alignas(16) unsigned short SH[4 * 16384];  // 128 KB ring

    const int tid  = threadIdx.x;
    const int lane = tid & 63;
    const int wid  = tid >> 6;
    const int wr   = wid >> 2;
    const int wc   = wid & 3;
    const int lr   = lane & 15;
    const int lg   = lane >> 4;

    const int L  = xcd_swz(blockIdx.x, KC * mt * nt);
    const int tn = (L % nt) << 8;
    const int r0 = L / nt;
    const int tm = (r0 % mt) << 8;
    const int kc = r0 / mt;
    const size_t kbase = (size_t)kc * KCH;

    const unsigned short* ag0 = A  + (size_t)(tm + (tid >> 2)) * Kd + kbase + ((tid & 3) << 3);
    const unsigned short* bg0 = Bm + (size_t)(tn + (tid >> 2)) * Kd + kbase + ((tid & 3) << 3);

    auto STAGE_A = [&](int tt) {
        const int buf = tt & 3;
        #pragma unroll
        for (int s = 0; s < 2; ++s)
            __builtin_amdgcn_global_load_lds(GPTR(ag0 + (size_t)(s * 128) * Kd + tt * 32),
                LPTR(&SH[buf * 16384 + s * 4096 + wid * 512]), 16, 0, 0);
    };
    auto STAGE_B = [&](int tt) {
        const int buf = tt & 3;
        #pragma unroll
        for (int s = 0; s < 2; ++s)
            __builtin_amdgcn_global_load_lds(GPTR(bg0 + (size_t)(s * 128) * Kd + tt * 32),
                LPTR(&SH[buf * 16384 + 8192 + s * 4096 + wid * 512]), 16, 0, 0);
    };

    f32x4 acc[8][4] = {};

    STAGE_A(0); STAGE_B(0);
    STAGE_A(1); STAGE_B(1);
    STAGE_A(2); STAGE_B(2);
    asm volatile("s_waitcnt vmcnt(8)" ::: "memory");
    __builtin_amdgcn_s_barrier();

    #pragma unroll 1
    for (int t = 0; t < NT; ++t) {
        if (t) {
            if (t < NT - 2)      asm volatile("s_waitcnt vmcnt(8)" ::: "memory");
            else if (t == NT-2)  asm volatile("s_waitcnt vmcnt(4)" ::: "memory");
            else                 asm volatile("s_waitcnt vmcnt(0)" ::: "memory");
            __builtin_amdgcn_s_barrier();
        }
        const int buf = t & 3;
        const unsigned short* Ab = &SH[buf * 16384];
        const unsigned short* Bb = &SH[buf * 16384 + 8192];

        // phase 1: read B(all) + A(lo); stage A(t+3); 16 MFMA
        bf16x8 bfr[4], af[4];
        #pragma unroll
        for (int ni = 0; ni < 4; ++ni)
            bfr[ni] = *(const bf16x8*)&Bb[(wc * 64 + ni * 16 + lr) * 32 + lg * 8];
        #pragma unroll
        for (int mi = 0; mi < 4; ++mi)
            af[mi] = *(const bf16x8*)&Ab[(wr * 128 + mi * 16 + lr) * 32 + lg * 8];
        if (t + 3 < NT) STAGE_A(t + 3);
        __builtin_amdgcn_sched_barrier(0);
        __builtin_amdgcn_s_setprio(1);
        #pragma unroll
        for (int mi = 0; mi < 4; ++mi)
            #pragma unroll
            for (int ni = 0; ni < 4; ++ni)
                acc[mi][ni] = __builtin_amdgcn_mfma_f32_16x16x32_bf16(af[mi], bfr[ni], acc[mi][ni], 0, 0, 0);
        __builtin_amdgcn_s_setprio(0);
        __builtin_amdgcn_s_barrier();

        // phase 2: read A(hi); stage B(t+3); 16 MFMA
        bf16x8 af2[4];
        #pragma unroll
        for (int mi = 0; mi < 4; ++mi)
            af2[mi] = *(const bf16x8*)&Ab[(wr * 128 + 64 + mi * 16 + lr) * 32 + lg * 8];
        if (t + 3 < NT) STAGE_B(t + 3);
        __builtin_amdgcn_sched_barrier(0);
        __builtin_amdgcn_s_setprio(1);
        #pragma unroll
        for (int mi = 0; mi < 4; ++mi)
            #pragma unroll
            for (int ni = 0; ni < 4; ++ni)
                acc[4 + mi][ni] = __builtin_amdgcn_mfma_f32_16x16x32_bf16(af2[mi], bfr[ni], acc[4 + mi][ni], 0, 0, 0);
        __builtin_amdgcn_s_setprio(0);
    }

    unsigned short* Ok = DIRECT ? (Out + (size_t)tm * No + tn)
                                : (Out + ((size_t)kc * Mo + tm) * No + tn);
    #pragma unroll
    for (int mi = 0; mi < 8; ++mi)
        #pragma unroll
        for (int ni = 0; ni < 4; ++ni)
            #pragma unroll
            for (int r = 0; r < 4; ++r) {
                const int row = wr * 128 + mi * 16 + lg * 4 + r;
                const int col = wc * 64 + ni * 16 + lr;
                Ok[(size_t)row * No + col] = f2bf(acc[mi][ni][r]);
            }
}

// ---------- reduce KC bf16 partials -> f32 ----------
template<int KC>
__global__ __launch_bounds__(256) void reduce_sk(
    const unsigned short* __restrict__ P, float* __restrict__ out, size_t total)
{
    const size_t i = ((size_t)blockIdx.x * 256 + threadIdx.x) * 8;
    float v[8] = {0,0,0,0,0,0,0,0};
    #pragma unroll
    for (int kc = 0; kc < KC; ++kc) {
        u16x8 p = *(const u16x8*)(P + kc * total + i);
        #pragma unroll
        for (int c = 0; c < 8; ++c) v[c] += bf2f(p[c]);
    }
    f32x4 o0, o1;
    #pragma unroll
    for (int c = 0; c < 4; ++c) { o0[c] = v[c]; o1[c] = v[4 + c]; }
    *(f32x4*)(out + i)     = o0;
    *(f32x4*)(out + i + 4) = o1;
}

// ---------- sparsemax over rows of bf16 scores; attn f32 out + attn bf16 in place ----------
__global__ __launch_bounds__(256) void sparsemax_k(unsigned short* __restrict__ SA,
                                                   float* __restrict__ attn)
{
    __shared__ float red[16];
    const int t = threadIdx.x;
    const int w = t >> 6, lane = t & 63;
    unsigned short* Zrow = SA + (size_t)blockIdx.x * FF;
    float* Arow = attn + (size_t)blockIdx.x * FF;

    f32x4 z[8];
    #pragma unroll
    for (int j = 0; j < 4; ++j) {
        u16x8 v = *(const u16x8*)&Zrow[j * 2048 + t * 8];
        #pragma unroll
        for (int c = 0; c < 4; ++c) {
            z[2 * j][c]     = bf2f(v[c]);
            z[2 * j + 1][c] = bf2f(v[4 + c]);
        }
    }

    float mx = -1e30f, sm = 0.0f;
    #pragma unroll
    for (int j = 0; j < 8; ++j)
        #pragma unroll
        for (int c = 0; c < 4; ++c) { mx = fmaxf(mx, z[j][c]); sm += z[j][c]; }
    #pragma unroll
    for (int off = 32; off > 0; off >>= 1) {
        mx = fmaxf(mx, __shfl_xor(mx, off));
        sm += __shfl_xor(sm, off);
    }
    if (lane == 0) { red[w] = mx; red[8 + w] = sm; }
    __syncthreads();
    mx = fmaxf(fmaxf(red[0], red[1]), fmaxf(red[2], red[3]));
    sm = red[8] + red[9] + red[10] + red[11];
    __syncthreads();

    float lo = fmaxf(mx - 1.0f, (sm - 1.0f) * (1.0f / (float)FF));
    float hi = mx - 1.0f / (float)FF;

    for (int it = 0; it < 8; ++it) {
        const float mid = 0.5f * (lo + hi);
        float s = 0.0f;
        #pragma unroll
        for (int j = 0; j < 8; ++j)
            #pragma unroll
            for (int c = 0; c < 4; ++c) s += fmaxf(z[j][c] - mid, 0.0f);
        #pragma unroll
        for (int off = 32; off > 0; off >>= 1) s += __shfl_xor(s, off);
        if (lane == 0) red[w] = s;
        __syncthreads();
        s = red[0] + red[1] + red[2] + red[3];
        __syncthreads();
        if (s >= 1.0f) lo = mid; else hi = mid;
    }

    for (int it = 0; it < 2; ++it) {
        float s = 0.0f, cnt = 0.0f;
        #pragma unroll
        for (int j = 0; j < 8; ++j)
            #pragma unroll
            for (int c = 0; c < 4; ++c) {
                const float v = z[j][c];
                if (v > lo) { s += v; cnt += 1.0f; }
            }
        #pragma unroll
        for (int off = 32; off > 0; off >>= 1) { s += __shfl_xor(s, off); cnt += __shfl_xor(cnt, off); }
        if (lane == 0) { red[w] = s; red[8 + w] = cnt; }
        __syncthreads();
        s   = red[0] + red[1] + red[2] + red[3];
        cnt = red[8] + red[9] + red[10] + red[11];
        __syncthreads();
        lo = (s - 1.0f) / cnt;
    }
    const float tau = lo;

    #pragma unroll
    for (int j = 0; j < 4; ++j) {
        f32x4 a0, a1;
        #pragma unroll
        for (int c = 0; c < 4; ++c) {
            a0[c] = fmaxf(z[2 * j][c] - tau, 0.0f);
            a1[c] = fmaxf(z[2 * j + 1][c] - tau, 0.0f);
        }
        *(f32x4*)&Arow[j * 2048 + t * 8]     = a0;
        *(f32x4*)&Arow[j * 2048 + t * 8 + 4] = a1;
        u16x8 o;
        #pragma unroll
        for (int c = 0; c < 4; ++c) { o[c] = f2bf(a0[c]); o[4 + c] = f2bf(a1[c]); }
        *(u16x8*)&Zrow[j * 2048 + t * 8] = o;
    }
}

// ---------- launch ----------
extern "C" void kernel_launch(void* const* d_in, const int* in_sizes, int n_in,
                              void* d_out, int out_size, void* d_ws, size_t ws_size,
                              hipStream_t stream) {
    const float* x  = (const float*)d_in[0];
    const float* Xd = (const float*)d_in[1];
    const float* Wq = (const float*)d_in[2];
    const float* bq = (const float*)d_in[3];
    const float* Wk = (const float*)d_in[4];
    const float* bk = (const float*)d_in[5];
    const float* Wv = (const float*)d_in[6];
    const float* bv = (const float*)d_in[7];

    float* out       = (float*)d_out;
    float* out_xhat  = out + (size_t)BB * DD;
    float* out_attn  = out + (size_t)2 * BB * DD;

    char* w = (char*)d_ws;
    unsigned short* xb  = (unsigned short*)w; w += (size_t)BB * DD * 2;   //  0-8 MB
    unsigned short* Xb  = (unsigned short*)w; w += (size_t)FF * DD * 2;   //  8-24 MB
    unsigned short* Wqb = (unsigned short*)w; w += (size_t)MM * DD * 2;
    unsigned short* Wkb = (unsigned short*)w; w += (size_t)MM * DD * 2;
    unsigned short* Wvb = (unsigned short*)w; w += (size_t)DD * DD * 2;
    unsigned short* Qb  = (unsigned short*)w; w += (size_t)BB * MM * 2;
    unsigned short* Kb  = (unsigned short*)w; w += (size_t)FF * MM * 2;   // ..33 MB
    unsigned short* Vtb = (unsigned short*)w; w += (size_t)DD * FF * 2;   // 33-49 MB
    unsigned short* Sb  = (unsigned short*)w; w += (size_t)BB * FF * 2;   // 49-113 MB

    // xhat partials 32 MB overlay xb..Kb (all dead at xhat time)
    unsigned short* Pb = (unsigned short*)d_ws;

    // 1: converts + x passthrough
    constexpr int CVT_N = BB * DD + FF * DD + 2 * MM * DD + DD * DD;
    cvt_all<<<CVT_N / 1024, 256, 0, stream>>>(x, Xd, Wq, Wk, Wv, out, xb, Xb, Wqb, Wkb, Wvb);

    // 2: all three projections, one dispatch (concurrent on-chip)
    proj_all<<<704, 256, 0, stream>>>(xb, Xb, Wqb, Wkb, Wvb, Qb, Kb, Vtb, bq, bk, bv, 0.0625f);

    // 3: scores = Q @ K^T  256x256 deep-pipe direct bf16 -> Sb
    gemm256<BB, FF, MM, 1, 1><<<(BB/256) * (FF/256), 512, 0, stream>>>(Qb, Kb, Sb);

    // 4: sparsemax: attn f32 -> d_out, attn bf16 in place over Sb
    sparsemax_k<<<BB, 256, 0, stream>>>(Sb, out_attn);

    // 5: x_hat = attn @ Vt^T  256x256 deep-pipe split-K x4 -> Pb
    gemm256<BB, DD, FF, 4, 0><<<4 * (BB/256) * (DD/256), 512, 0, stream>>>(Sb, Vtb, Pb);

    // 6: reduce partials -> f32 x_hat
    reduce_sk<4><<<BB * DD / 2048, 256, 0, stream>>>(Pb, out_xhat, (size_t)BB * DD);
}